// Round 4
// baseline (639.535 us; speedup 1.0000x reference)
//
#include <hip/hip_runtime.h>
#include <hip/hip_bf16.h>

#define DF 256
#define KC 64

__device__ __forceinline__ float waveReduceSum(float v) {
    #pragma unroll
    for (int off = 32; off; off >>= 1) v += __shfl_xor(v, off, 64);
    return v;
}

// ---------------- sentinel fill (f32) ----------------
__global__ void k_sentinel(float* __restrict__ out, float val, int n) {
    int i = blockIdx.x * blockDim.x + threadIdx.x;
    int st = gridDim.x * blockDim.x;
    for (; i < n; i += st) out[i] = val;
}

// ---------------- K0: zero small accumulator region in ws ----------------
__global__ void k_zero(float* __restrict__ p, int n) {
    int i = blockIdx.x * blockDim.x + threadIdx.x;
    int st = gridDim.x * blockDim.x;
    for (; i < n; i += st) p[i] = 0.f;
}

// ---------------- K1 (SIMPLE): logits = F@W + b, softmax -> f32 S (in d_out) ----
// wave per row, lane = cluster k, broadcast scalar F loads, W in LDS.
__global__ __launch_bounds__(256) void k_assign(
    const float* __restrict__ F, const float* __restrict__ W,
    const float* __restrict__ B, float* __restrict__ S, int N)
{
    __shared__ float Wl[DF * KC];   // 64 KB: W[d][k] row-major
    for (int i = threadIdx.x; i < DF * KC; i += 256) Wl[i] = W[i];
    __syncthreads();
    const int lane = threadIdx.x & 63;
    const int wv = threadIdx.x >> 6;
    const float bv = B[lane];
    for (int row = blockIdx.x * 4 + wv; row < N; row += gridDim.x * 4) {
        const float* fp = F + (size_t)row * DF;
        float acc = bv;
        for (int d = 0; d < DF; ++d) {
            acc = fmaf(fp[d], Wl[d * KC + lane], acc);   // fp[d]: wave-uniform broadcast
        }
        // wave softmax over 64 lanes (lane = cluster k)
        float m = acc;
        #pragma unroll
        for (int off = 32; off; off >>= 1) m = fmaxf(m, __shfl_xor(m, off, 64));
        float e = expf(acc - m);
        float s = waveReduceSum(e);
        S[(size_t)row * KC + lane] = e / s;
    }
}

// ---------------- K2: per edge-set: tr = sum_e v*<S_r,S_c>; Sd[k] += v*S[c,k]; ne = sum v ----
__global__ __launch_bounds__(256) void k_edge(
    const int* __restrict__ r, const int* __restrict__ c, const float* __restrict__ v, int E,
    const float* __restrict__ S,
    float* __restrict__ trp, float* __restrict__ nep, float* __restrict__ Sd)
{
    const int lane = threadIdx.x & 63;
    const int wid = (blockIdx.x * blockDim.x + threadIdx.x) >> 6;
    const int nw = (gridDim.x * blockDim.x) >> 6;
    const int nch = (E + 63) >> 6;
    float tr = 0.f, sd = 0.f, ne = 0.f;
    for (int ch = wid; ch < nch; ch += nw) {
        int idx = (ch << 6) + lane;
        bool ok = idx < E;
        int rr0 = ok ? r[idx] : 0;
        int cc0 = ok ? c[idx] : 0;
        float vv0 = ok ? v[idx] : 0.f;
        ne += vv0;
        #pragma unroll 4
        for (int j = 0; j < 64; ++j) {
            int rr = __shfl(rr0, j, 64);
            int cc = __shfl(cc0, j, 64);
            float vv = __shfl(vv0, j, 64);
            float sr = S[(size_t)rr * KC + lane];
            float sc = S[(size_t)cc * KC + lane];
            tr += vv * sr * sc;
            sd += vv * sc;
        }
    }
    tr = waveReduceSum(tr);
    ne = waveReduceSum(ne);
    if (lane == 0) { atomicAdd(trp, tr); atomicAdd(nep, ne); }
    atomicAdd(Sd + lane, sd);
}

// ---------------- K3: cs[k] = sum_n S[n,k] ----------------
__global__ __launch_bounds__(256) void k_cs(
    const float* __restrict__ S, float* __restrict__ cs, int N)
{
    const int lane = threadIdx.x & 63;
    const int wid = (blockIdx.x * blockDim.x + threadIdx.x) >> 6;
    const int nw = (gridDim.x * blockDim.x) >> 6;
    float a = 0.f;
    for (int row = wid; row < N; row += nw)
        a += S[(size_t)row * KC + lane];
    atomicAdd(cs + lane, a);
}

// ---------------- K4 (SIMPLE): P[k,d] = sum_n S[n,k] * F[n,d] ----------------
// thread = d; rows partitioned by block; S reads are thread-uniform broadcasts.
__global__ __launch_bounds__(256) void k_pool(
    const float* __restrict__ S, const float* __restrict__ F,
    float* __restrict__ P, int N)
{
    const int d = threadIdx.x;      // 0..255 = feature dim
    float acc[KC];
    #pragma unroll
    for (int k = 0; k < KC; ++k) acc[k] = 0.f;
    int rowsPer = (N + gridDim.x - 1) / gridDim.x;
    int n0 = blockIdx.x * rowsPer;
    int n1 = min(N, n0 + rowsPer);
    for (int n = n0; n < n1; ++n) {
        float fv = F[(size_t)n * DF + d];          // coalesced
        const float* sp = S + (size_t)n * KC;
        #pragma unroll
        for (int k = 0; k < KC; ++k)
            acc[k] = fmaf(sp[k], fv, acc[k]);      // broadcast
    }
    #pragma unroll
    for (int k = 0; k < KC; ++k) atomicAdd(P + k * DF + d, acc[k]);
}

// ---------------- K5: epilogue: selu(P/cs) + total loss ----------------
__global__ __launch_bounds__(256) void k_final(
    const float* __restrict__ P, const float* __restrict__ cs,
    const float* __restrict__ scal,
    const float* __restrict__ Sd,   // [3][KC]: F,R,B
    const float* __restrict__ lamdaPtr,
    float* __restrict__ out, int N, int lossIdx)
{
    const float SC = 1.0507009873554805f, AL = 1.6732632423543772f;
    for (int i = threadIdx.x + blockIdx.x * blockDim.x; i < KC * DF; i += gridDim.x * blockDim.x) {
        int k = i / DF;
        float x = P[i] / cs[k];
        float y = x > 0.f ? SC * x : SC * AL * (expf(x) - 1.f);
        out[i] = y;
    }
    if (blockIdx.x == 0 && threadIdx.x == 0) {
        float trF = scal[0], trR = scal[1], trB = scal[2];
        float neF = scal[3], neR = scal[4], neB = scal[5];
        float two_m = neF;
        float sdf = 0.f, sdr = 0.f, sdb = 0.f, csn = 0.f;
        for (int k = 0; k < KC; ++k) {
            sdf += Sd[0 * KC + k] * Sd[0 * KC + k];
            sdr += Sd[1 * KC + k] * Sd[1 * KC + k];
            sdb += Sd[2 * KC + k] * Sd[2 * KC + k];
            csn += cs[k] * cs[k];
        }
        float lossF = -(trF - sdf / 2.f / neF) / 2.f / two_m;
        float lossR = -(trR - sdr / 2.f / neR) / 2.f / two_m;
        float lossB = -(trB - sdb / 2.f / neB) / 2.f / two_m;
        float fairness = fabsf(lamdaPtr[0] * (lossR - lossB));
        float collapse = sqrtf(csn) / (float)N * sqrtf((float)KC) - 1.f;
        float total = fairness + lossF + 0.1f * collapse;
        out[lossIdx] = total;
    }
}

extern "C" void kernel_launch(void* const* d_in, const int* in_sizes, int n_in,
                              void* d_out, int out_size, void* d_ws, size_t ws_size,
                              hipStream_t stream) {
    float* out = (float*)d_out;

    // ---- diagnostic sentinels (host-side branches on host-constant values) ----
    const int expected_sizes[13] = {12800000, 1600000, 1600000, 1600000,
                                    800000, 800000, 800000, 800000, 800000, 800000,
                                    16384, 64, 1};
    bool sizes_ok = (n_in == 13) && (out_size == 16384 + 12800000 / DF * KC + 1);
    if (sizes_ok) for (int i = 0; i < 13; ++i) if (in_sizes[i] != expected_sizes[i]) sizes_ok = false;
    if (!sizes_ok) {
        k_sentinel<<<64, 256, 0, stream>>>(out, 22222.0f, KC * DF);
        return;
    }
    const size_t wsNeeded = (size_t)(16 + KC + 3 * KC + KC * DF) * sizeof(float);
    if (ws_size < wsNeeded) {
        k_sentinel<<<64, 256, 0, stream>>>(out, 11111.0f, KC * DF);
        return;
    }

    const float* F  = (const float*)d_in[0];
    const int*   rF = (const int*)  d_in[1];
    const int*   cF = (const int*)  d_in[2];
    const float* vF = (const float*)d_in[3];
    const int*   rR = (const int*)  d_in[4];
    const int*   cR = (const int*)  d_in[5];
    const float* vR = (const float*)d_in[6];
    const int*   rB = (const int*)  d_in[7];
    const int*   cB = (const int*)  d_in[8];
    const float* vB = (const float*)d_in[9];
    const float* W  = (const float*)d_in[10];
    const float* B  = (const float*)d_in[11];
    const float* lam= (const float*)d_in[12];

    const int E   = in_sizes[1];
    const int E2r = in_sizes[4];
    const int E2b = in_sizes[7];
    const int N   = in_sizes[0] / DF;

    float* S = out + KC * DF;          // S [N,K] f32 lives in the output buffer

    // tiny workspace layout (f32): scal[16], cs[64], Sd[3*64], P[64*256]
    float* scal = (float*)d_ws;   // [0..2]=tr F/R/B, [3..5]=ne F/R/B
    float* cs   = scal + 16;
    float* Sd   = cs + KC;
    float* P    = Sd + 3 * KC;
    const int zeroCount = 16 + KC + 3 * KC + KC * DF;

    k_zero  <<<64, 256, 0, stream>>>(scal, zeroCount);
    k_assign<<<2048, 256, 0, stream>>>(F, W, B, S, N);
    k_edge  <<<1024, 256, 0, stream>>>(rF, cF, vF, E,   S, scal + 0, scal + 3, Sd + 0 * KC);
    k_edge  <<<512, 256, 0, stream>>>(rR, cR, vR, E2r, S, scal + 1, scal + 4, Sd + 1 * KC);
    k_edge  <<<512, 256, 0, stream>>>(rB, cB, vB, E2b, S, scal + 2, scal + 5, Sd + 2 * KC);
    k_cs    <<<256, 256, 0, stream>>>(S, cs, N);
    k_pool  <<<256, 256, 0, stream>>>(S, F, P, N);
    k_final <<<64, 256, 0, stream>>>(P, cs, scal, Sd, lam, out, N, out_size - 1);
}

// Round 5
// 453.870 us; speedup vs baseline: 1.4091x; 1.4091x over previous
//
#include <hip/hip_runtime.h>
#include <hip/hip_bf16.h>

#define DF 256
#define KC 64

__device__ __forceinline__ float waveReduceSum(float v) {
    #pragma unroll
    for (int off = 32; off; off >>= 1) v += __shfl_xor(v, off, 64);
    return v;
}

__device__ __forceinline__ float ldS(const float* p) { return *p; }
__device__ __forceinline__ float ldS(const __hip_bfloat16* p) { return __bfloat162float(*p); }

// ---------------- sentinel fill (f32) ----------------
__global__ void k_sentinel(float* __restrict__ out, float val, int n) {
    int i = blockIdx.x * blockDim.x + threadIdx.x;
    int st = gridDim.x * blockDim.x;
    for (; i < n; i += st) out[i] = val;
}

// ---------------- K0: zero small accumulator region in ws ----------------
__global__ void k_zero(float* __restrict__ p, int n) {
    int i = blockIdx.x * blockDim.x + threadIdx.x;
    int st = gridDim.x * blockDim.x;
    for (; i < n; i += st) p[i] = 0.f;
}

// ---------------- K1: logits = F@W + b, softmax -> f32 S (+ bf16 shadow) ----
// wave per row, lane = cluster k. float4 row load + shfl broadcast; W in LDS.
__global__ __launch_bounds__(256) void k_assign(
    const float* __restrict__ F, const float* __restrict__ W,
    const float* __restrict__ B, float* __restrict__ S,
    __hip_bfloat16* __restrict__ S16, int N, int writeBf16)
{
    __shared__ float Wl[DF * KC];   // 64 KB: W[d][k]
    for (int i = threadIdx.x; i < DF * KC; i += 256) Wl[i] = W[i];
    __syncthreads();
    const int lane = threadIdx.x & 63;
    const int wv = threadIdx.x >> 6;
    const float bv = B[lane];
    for (int row = blockIdx.x * 4 + wv; row < N; row += gridDim.x * 4) {
        float4 fr = reinterpret_cast<const float4*>(F + (size_t)row * DF)[lane];
        float acc = bv;
        #pragma unroll
        for (int dd = 0; dd < 64; ++dd) {
            float b0 = __shfl(fr.x, dd, 64);
            float b1 = __shfl(fr.y, dd, 64);
            float b2 = __shfl(fr.z, dd, 64);
            float b3 = __shfl(fr.w, dd, 64);
            acc = fmaf(b0, Wl[(4 * dd + 0) * KC + lane], acc);
            acc = fmaf(b1, Wl[(4 * dd + 1) * KC + lane], acc);
            acc = fmaf(b2, Wl[(4 * dd + 2) * KC + lane], acc);
            acc = fmaf(b3, Wl[(4 * dd + 3) * KC + lane], acc);
        }
        float m = acc;
        #pragma unroll
        for (int off = 32; off; off >>= 1) m = fmaxf(m, __shfl_xor(m, off, 64));
        float e = expf(acc - m);
        float s = waveReduceSum(e);
        float p = e / s;
        S[(size_t)row * KC + lane] = p;
        if (writeBf16) S16[(size_t)row * KC + lane] = __float2bfloat16(p);
    }
}

// ---------------- K2 (fused, all 3 edge sets): tr, Sd, ne per set ----------------
template <typename T>
__global__ __launch_bounds__(256) void k_edge3(
    const int* __restrict__ rF, const int* __restrict__ cF, const float* __restrict__ vF, int EF,
    const int* __restrict__ rR, const int* __restrict__ cR, const float* __restrict__ vR, int ER,
    const int* __restrict__ rB, const int* __restrict__ cB, const float* __restrict__ vB, int EB,
    const T* __restrict__ S, float* __restrict__ scal, float* __restrict__ Sd)
{
    __shared__ float sdl[3][4][KC];   // per-set, per-wave partial Sd
    __shared__ float red[4][6];       // per-wave tr0,tr1,tr2,ne0,ne1,ne2
    const int lane = threadIdx.x & 63;
    const int wv = threadIdx.x >> 6;
    const int wid = (blockIdx.x * blockDim.x + threadIdx.x) >> 6;
    const int nw = (gridDim.x * blockDim.x) >> 6;
    const int chF = (EF + 63) >> 6, chR = (ER + 63) >> 6, chB = (EB + 63) >> 6;
    const int tot = chF + chR + chB;
    float tr0 = 0.f, tr1 = 0.f, tr2 = 0.f;
    float sd0 = 0.f, sd1 = 0.f, sd2 = 0.f;
    float ne0 = 0.f, ne1 = 0.f, ne2 = 0.f;
    for (int ch = wid; ch < tot; ch += nw) {
        const int *rp, *cp; const float* vp; int base, len, seg;
        if (ch < chF)            { rp = rF; cp = cF; vp = vF; base = ch << 6;               len = EF; seg = 0; }
        else if (ch < chF + chR) { rp = rR; cp = cR; vp = vR; base = (ch - chF) << 6;       len = ER; seg = 1; }
        else                     { rp = rB; cp = cB; vp = vB; base = (ch - chF - chR) << 6; len = EB; seg = 2; }
        int idx = base + lane;
        bool ok = idx < len;
        int r0 = ok ? rp[idx] : 0;
        int c0 = ok ? cp[idx] : 0;
        float v0 = ok ? vp[idx] : 0.f;
        float t = 0.f, s = 0.f;
        #pragma unroll 8
        for (int j = 0; j < 64; ++j) {
            int rr = __shfl(r0, j, 64);
            int cc = __shfl(c0, j, 64);
            float vv = __shfl(v0, j, 64);
            float sr = ldS(S + (size_t)rr * KC + lane);
            float sc = ldS(S + (size_t)cc * KC + lane);
            t = fmaf(vv * sr, sc, t);
            s = fmaf(vv, sc, s);
        }
        if (seg == 0)      { tr0 += t; sd0 += s; ne0 += v0; }
        else if (seg == 1) { tr1 += t; sd1 += s; ne1 += v0; }
        else               { tr2 += t; sd2 += s; ne2 += v0; }
    }
    sdl[0][wv][lane] = sd0;
    sdl[1][wv][lane] = sd1;
    sdl[2][wv][lane] = sd2;
    float t0 = waveReduceSum(tr0), t1 = waveReduceSum(tr1), t2 = waveReduceSum(tr2);
    float n0 = waveReduceSum(ne0), n1 = waveReduceSum(ne1), n2 = waveReduceSum(ne2);
    if (lane == 0) {
        red[wv][0] = t0; red[wv][1] = t1; red[wv][2] = t2;
        red[wv][3] = n0; red[wv][4] = n1; red[wv][5] = n2;
    }
    __syncthreads();
    if (threadIdx.x < KC) {
        #pragma unroll
        for (int s2 = 0; s2 < 3; ++s2) {
            float a = sdl[s2][0][threadIdx.x] + sdl[s2][1][threadIdx.x]
                    + sdl[s2][2][threadIdx.x] + sdl[s2][3][threadIdx.x];
            atomicAdd(Sd + s2 * KC + threadIdx.x, a);
        }
    } else if (threadIdx.x < KC + 6) {
        int q = threadIdx.x - KC;   // 0..2 -> tr F/R/B (scal[0..2]), 3..5 -> ne F/R/B (scal[3..5])
        float a = red[0][q] + red[1][q] + red[2][q] + red[3][q];
        atomicAdd(scal + q, a);
    }
}

// ---------------- K3: cs[k] = sum_n S[n,k] ----------------
__global__ __launch_bounds__(256) void k_cs(
    const float* __restrict__ S, float* __restrict__ cs, int N)
{
    const int lane = threadIdx.x & 63;
    const int wid = (blockIdx.x * blockDim.x + threadIdx.x) >> 6;
    const int nw = (gridDim.x * blockDim.x) >> 6;
    float a = 0.f;
    for (int row = wid; row < N; row += nw)
        a += S[(size_t)row * KC + lane];
    atomicAdd(cs + lane, a);
}

// ---------------- K4: P[k,d] = sum_n S[n,k] * F[n,d] ----------------
__global__ __launch_bounds__(256) void k_pool(
    const float* __restrict__ S, const float* __restrict__ F,
    float* __restrict__ P, int N)
{
    const int d = threadIdx.x;      // 0..255 = feature dim
    float acc[KC];
    #pragma unroll
    for (int k = 0; k < KC; ++k) acc[k] = 0.f;
    int rowsPer = (N + gridDim.x - 1) / gridDim.x;
    int n0 = blockIdx.x * rowsPer;
    int n1 = min(N, n0 + rowsPer);
    for (int n = n0; n < n1; ++n) {
        float fv = F[(size_t)n * DF + d];          // coalesced
        const float* sp = S + (size_t)n * KC;
        #pragma unroll
        for (int k = 0; k < KC; ++k)
            acc[k] = fmaf(sp[k], fv, acc[k]);      // wave-uniform broadcast
    }
    #pragma unroll
    for (int k = 0; k < KC; ++k) atomicAdd(P + k * DF + d, acc[k]);
}

// ---------------- K5: epilogue: selu(P/cs) + total loss ----------------
__global__ __launch_bounds__(256) void k_final(
    const float* __restrict__ P, const float* __restrict__ cs,
    const float* __restrict__ scal,
    const float* __restrict__ Sd,   // [3][KC]: F,R,B
    const float* __restrict__ lamdaPtr,
    float* __restrict__ out, int N, int lossIdx)
{
    const float SC = 1.0507009873554805f, AL = 1.6732632423543772f;
    for (int i = threadIdx.x + blockIdx.x * blockDim.x; i < KC * DF; i += gridDim.x * blockDim.x) {
        int k = i / DF;
        float x = P[i] / cs[k];
        float y = x > 0.f ? SC * x : SC * AL * (expf(x) - 1.f);
        out[i] = y;
    }
    if (blockIdx.x == 0 && threadIdx.x == 0) {
        float trF = scal[0], trR = scal[1], trB = scal[2];
        float neF = scal[3], neR = scal[4], neB = scal[5];
        float two_m = neF;
        float sdf = 0.f, sdr = 0.f, sdb = 0.f, csn = 0.f;
        for (int k = 0; k < KC; ++k) {
            sdf += Sd[0 * KC + k] * Sd[0 * KC + k];
            sdr += Sd[1 * KC + k] * Sd[1 * KC + k];
            sdb += Sd[2 * KC + k] * Sd[2 * KC + k];
            csn += cs[k] * cs[k];
        }
        float lossF = -(trF - sdf / 2.f / neF) / 2.f / two_m;
        float lossR = -(trR - sdr / 2.f / neR) / 2.f / two_m;
        float lossB = -(trB - sdb / 2.f / neB) / 2.f / two_m;
        float fairness = fabsf(lamdaPtr[0] * (lossR - lossB));
        float collapse = sqrtf(csn) / (float)N * sqrtf((float)KC) - 1.f;
        float total = fairness + lossF + 0.1f * collapse;
        out[lossIdx] = total;
    }
}

extern "C" void kernel_launch(void* const* d_in, const int* in_sizes, int n_in,
                              void* d_out, int out_size, void* d_ws, size_t ws_size,
                              hipStream_t stream) {
    float* out = (float*)d_out;

    // ---- diagnostic sentinels (host-side branches on host-constant values) ----
    const int expected_sizes[13] = {12800000, 1600000, 1600000, 1600000,
                                    800000, 800000, 800000, 800000, 800000, 800000,
                                    16384, 64, 1};
    bool sizes_ok = (n_in == 13) && (out_size == 16384 + 12800000 / DF * KC + 1);
    if (sizes_ok) for (int i = 0; i < 13; ++i) if (in_sizes[i] != expected_sizes[i]) sizes_ok = false;
    if (!sizes_ok) {
        k_sentinel<<<64, 256, 0, stream>>>(out, 22222.0f, KC * DF);
        return;
    }

    const float* F  = (const float*)d_in[0];
    const int*   rF = (const int*)  d_in[1];
    const int*   cF = (const int*)  d_in[2];
    const float* vF = (const float*)d_in[3];
    const int*   rR = (const int*)  d_in[4];
    const int*   cR = (const int*)  d_in[5];
    const float* vR = (const float*)d_in[6];
    const int*   rB = (const int*)  d_in[7];
    const int*   cB = (const int*)  d_in[8];
    const float* vB = (const float*)d_in[9];
    const float* W  = (const float*)d_in[10];
    const float* B  = (const float*)d_in[11];
    const float* lam= (const float*)d_in[12];

    const int E   = in_sizes[1];
    const int E2r = in_sizes[4];
    const int E2b = in_sizes[7];
    const int N   = in_sizes[0] / DF;

    float* S = out + KC * DF;          // S [N,K] f32 in the output buffer

    // ws layout: [optional bf16 S shadow: N*KC*2][f32: scal 16 | cs 64 | Sd 192 | P 16384]
    const size_t s16Bytes = (size_t)N * KC * sizeof(__hip_bfloat16);
    const size_t f32Bytes = (size_t)(16 + KC + 3 * KC + KC * DF) * sizeof(float);
    const bool useBf16 = ws_size >= s16Bytes + f32Bytes;
    if (!useBf16 && ws_size < f32Bytes) {
        k_sentinel<<<64, 256, 0, stream>>>(out, 11111.0f, KC * DF);
        return;
    }
    __hip_bfloat16* S16 = (__hip_bfloat16*)d_ws;
    float* fbase = useBf16 ? (float*)((char*)d_ws + s16Bytes) : (float*)d_ws;
    float* scal = fbase;          // [0..2]=tr F/R/B, [3..5]=ne F/R/B
    float* cs   = scal + 16;
    float* Sd   = cs + KC;
    float* P    = Sd + 3 * KC;
    const int zeroCount = 16 + KC + 3 * KC + KC * DF;

    k_zero  <<<64, 256, 0, stream>>>(scal, zeroCount);
    k_assign<<<2048, 256, 0, stream>>>(F, W, B, S, S16, N, useBf16 ? 1 : 0);
    if (useBf16) {
        k_edge3<__hip_bfloat16><<<2048, 256, 0, stream>>>(
            rF, cF, vF, E, rR, cR, vR, E2r, rB, cB, vB, E2b, S16, scal, Sd);
    } else {
        k_edge3<float><<<2048, 256, 0, stream>>>(
            rF, cF, vF, E, rR, cR, vR, E2r, rB, cB, vB, E2b, S, scal, Sd);
    }
    k_cs    <<<512, 256, 0, stream>>>(S, cs, N);
    k_pool  <<<512, 256, 0, stream>>>(S, F, P, N);
    k_final <<<64, 256, 0, stream>>>(P, cs, scal, Sd, lam, out, N, out_size - 1);
}

// Round 6
// 302.040 us; speedup vs baseline: 2.1174x; 1.5027x over previous
//
#include <hip/hip_runtime.h>
#include <hip/hip_bf16.h>

#define DF 256
#define KC 64

typedef __attribute__((ext_vector_type(8))) short short8v;
typedef __attribute__((ext_vector_type(4))) float float4v;

__device__ __forceinline__ float waveReduceSum(float v) {
    #pragma unroll
    for (int off = 32; off; off >>= 1) v += __shfl_xor(v, off, 64);
    return v;
}

__device__ __forceinline__ float ldS(const float* p) { return *p; }
__device__ __forceinline__ float ldS(const __hip_bfloat16* p) { return __bfloat162float(*p); }

__device__ __forceinline__ void splitbf(float f, short& hi, short& lo) {
    unsigned u = __float_as_uint(f);
    hi = (short)(u >> 16);                       // truncated bf16 hi
    float r = f - __uint_as_float(u & 0xFFFF0000u);
    __hip_bfloat16 lb = __float2bfloat16(r);     // RNE lo
    lo = *reinterpret_cast<short*>(&lb);
}

// ---------------- sentinel fill (f32) ----------------
__global__ void k_sentinel(float* __restrict__ out, float val, int n) {
    int i = blockIdx.x * blockDim.x + threadIdx.x;
    int st = gridDim.x * blockDim.x;
    for (; i < n; i += st) out[i] = val;
}

// ---------------- K0: zero small accumulator region in ws ----------------
__global__ void k_zero(float* __restrict__ p, int n) {
    int i = blockIdx.x * blockDim.x + threadIdx.x;
    int st = gridDim.x * blockDim.x;
    for (; i < n; i += st) p[i] = 0.f;
}

// ---------------- prep: W [256][64] f32 -> frag-packed bf16 hi/lo ----------------
// element (k,c), k = kk*32 + g*8 + j  ->  dst = ((kk*4+g)*64 + c)*8 + j
__global__ void k_prepW(const float* __restrict__ W, ushort* __restrict__ W2) {
    int i = blockIdx.x * blockDim.x + threadIdx.x;
    if (i >= DF * KC) return;
    int k = i >> 6, c = i & 63;
    int kk = k >> 5, g = (k >> 3) & 3, j = k & 7;
    int dst = ((kk * 4 + g) * 64 + c) * 8 + j;
    short hi, lo;
    splitbf(W[i], hi, lo);
    W2[dst] = (ushort)hi;
    W2[DF * KC + dst] = (ushort)lo;
}

// ---------------- K1 (MFMA): logits = F@W + b (split-bf16 x3), softmax, cs ----
__global__ __launch_bounds__(256) void k_assign_mfma(
    const float* __restrict__ F, const ushort* __restrict__ W2,
    const float* __restrict__ Bias, float* __restrict__ S,
    __hip_bfloat16* __restrict__ S16, float* __restrict__ cs,
    int N, int writeBf16)
{
    __shared__ ushort W2s[2 * DF * KC];   // 64 KB: hi [0..16384), lo [16384..)
    {
        const int4* src = (const int4*)W2;
        int4* dst = (int4*)W2s;
        for (int i = threadIdx.x; i < 4096; i += 256) dst[i] = src[i];
    }
    __syncthreads();
    const int lane = threadIdx.x & 63;
    const int wv = threadIdx.x >> 6;
    const int lw = lane & 15, g = lane >> 4;
    const int NT = (N + 15) >> 4;
    const int t = blockIdx.x * 4 + wv;
    if (t < NT) {
        const int r0 = t * 16;
        int arowi = r0 + lw; if (arowi >= N) arowi = N - 1;
        const float* arow = F + (size_t)arowi * DF + g * 8;
        short8v ahi[8], alo[8];
        #pragma unroll
        for (int kk = 0; kk < 8; ++kk) {
            float4 x = *(const float4*)(arow + kk * 32);
            float4 y = *(const float4*)(arow + kk * 32 + 4);
            float xf[8] = {x.x, x.y, x.z, x.w, y.x, y.y, y.z, y.w};
            #pragma unroll
            for (int j = 0; j < 8; ++j) {
                short hi, lo; splitbf(xf[j], hi, lo);
                ahi[kk][j] = hi; alo[kk][j] = lo;
            }
        }
        float4v acc[4];
        #pragma unroll
        for (int ct = 0; ct < 4; ++ct) {
            float bv = Bias[ct * 16 + lw];
            acc[ct] = float4v{bv, bv, bv, bv};
        }
        #pragma unroll
        for (int kk = 0; kk < 8; ++kk) {
            #pragma unroll
            for (int ct = 0; ct < 4; ++ct) {
                int eb = ((kk * 4 + g) * 64 + ct * 16 + lw) * 8;
                short8v bhi = *(short8v*)(&W2s[eb]);
                short8v blo = *(short8v*)(&W2s[DF * KC + eb]);
                acc[ct] = __builtin_amdgcn_mfma_f32_16x16x32_bf16(ahi[kk], bhi, acc[ct], 0, 0, 0);
                acc[ct] = __builtin_amdgcn_mfma_f32_16x16x32_bf16(ahi[kk], blo, acc[ct], 0, 0, 0);
                acc[ct] = __builtin_amdgcn_mfma_f32_16x16x32_bf16(alo[kk], bhi, acc[ct], 0, 0, 0);
            }
        }
        // softmax per row (row = r0 + g*4 + r), cols spread over ct (x16) and lw
        float csp[4] = {0.f, 0.f, 0.f, 0.f};
        #pragma unroll
        for (int r = 0; r < 4; ++r) {
            float m = fmaxf(fmaxf(acc[0][r], acc[1][r]), fmaxf(acc[2][r], acc[3][r]));
            #pragma unroll
            for (int off = 8; off; off >>= 1) m = fmaxf(m, __shfl_xor(m, off, 64));
            float e0 = expf(acc[0][r] - m), e1 = expf(acc[1][r] - m);
            float e2 = expf(acc[2][r] - m), e3 = expf(acc[3][r] - m);
            float s = e0 + e1 + e2 + e3;
            #pragma unroll
            for (int off = 8; off; off >>= 1) s += __shfl_xor(s, off, 64);
            float inv = 1.f / s;
            e0 *= inv; e1 *= inv; e2 *= inv; e3 *= inv;
            int rw = r0 + g * 4 + r;
            if (rw < N) {
                size_t base = (size_t)rw * KC + lw;
                S[base +  0] = e0; S[base + 16] = e1;
                S[base + 32] = e2; S[base + 48] = e3;
                if (writeBf16) {
                    S16[base +  0] = __float2bfloat16(e0);
                    S16[base + 16] = __float2bfloat16(e1);
                    S16[base + 32] = __float2bfloat16(e2);
                    S16[base + 48] = __float2bfloat16(e3);
                }
                csp[0] += e0; csp[1] += e1; csp[2] += e2; csp[3] += e3;
            }
        }
        #pragma unroll
        for (int ct = 0; ct < 4; ++ct) {
            csp[ct] += __shfl_xor(csp[ct], 16, 64);
            csp[ct] += __shfl_xor(csp[ct], 32, 64);
        }
        if (g == 0) {
            #pragma unroll
            for (int ct = 0; ct < 4; ++ct) atomicAdd(cs + ct * 16 + lw, csp[ct]);
        }
    }
}

// ---------------- K1 fallback (VALU, small ws): logits+softmax ----------------
__global__ __launch_bounds__(256) void k_assign_valu(
    const float* __restrict__ F, const float* __restrict__ W,
    const float* __restrict__ B, float* __restrict__ S, int N)
{
    __shared__ float Wl[DF * KC];
    for (int i = threadIdx.x; i < DF * KC; i += 256) Wl[i] = W[i];
    __syncthreads();
    const int lane = threadIdx.x & 63;
    const int wv = threadIdx.x >> 6;
    const float bv = B[lane];
    for (int row = blockIdx.x * 4 + wv; row < N; row += gridDim.x * 4) {
        const float* fp = F + (size_t)row * DF;
        float acc = bv;
        for (int d = 0; d < DF; ++d) acc = fmaf(fp[d], Wl[d * KC + lane], acc);
        float m = acc;
        #pragma unroll
        for (int off = 32; off; off >>= 1) m = fmaxf(m, __shfl_xor(m, off, 64));
        float e = expf(acc - m);
        float s = waveReduceSum(e);
        S[(size_t)row * KC + lane] = e / s;
    }
}

// ---------------- K2 (fused, all 3 edge sets): tr, Sd, ne per set ----------------
template <typename T>
__global__ __launch_bounds__(256) void k_edge3(
    const int* __restrict__ rF, const int* __restrict__ cF, const float* __restrict__ vF, int EF,
    const int* __restrict__ rR, const int* __restrict__ cR, const float* __restrict__ vR, int ER,
    const int* __restrict__ rB, const int* __restrict__ cB, const float* __restrict__ vB, int EB,
    const T* __restrict__ S, float* __restrict__ scal, float* __restrict__ Sd)
{
    __shared__ float sdl[3][4][KC];
    __shared__ float red[4][6];
    const int lane = threadIdx.x & 63;
    const int wv = threadIdx.x >> 6;
    const int wid = (blockIdx.x * blockDim.x + threadIdx.x) >> 6;
    const int nw = (gridDim.x * blockDim.x) >> 6;
    const int chF = (EF + 63) >> 6, chR = (ER + 63) >> 6, chB = (EB + 63) >> 6;
    const int tot = chF + chR + chB;
    float tr0 = 0.f, tr1 = 0.f, tr2 = 0.f;
    float sd0 = 0.f, sd1 = 0.f, sd2 = 0.f;
    float ne0 = 0.f, ne1 = 0.f, ne2 = 0.f;
    for (int ch = wid; ch < tot; ch += nw) {
        const int *rp, *cp; const float* vp; int base, len, seg;
        if (ch < chF)            { rp = rF; cp = cF; vp = vF; base = ch << 6;               len = EF; seg = 0; }
        else if (ch < chF + chR) { rp = rR; cp = cR; vp = vR; base = (ch - chF) << 6;       len = ER; seg = 1; }
        else                     { rp = rB; cp = cB; vp = vB; base = (ch - chF - chR) << 6; len = EB; seg = 2; }
        int idx = base + lane;
        bool ok = idx < len;
        int r0 = ok ? rp[idx] : 0;
        int c0 = ok ? cp[idx] : 0;
        float v0 = ok ? vp[idx] : 0.f;
        float t = 0.f, s = 0.f;
        #pragma unroll 8
        for (int j = 0; j < 64; ++j) {
            int rr = __shfl(r0, j, 64);
            int cc = __shfl(c0, j, 64);
            float vv = __shfl(v0, j, 64);
            float sr = ldS(S + (size_t)rr * KC + lane);
            float sc = ldS(S + (size_t)cc * KC + lane);
            t = fmaf(vv * sr, sc, t);
            s = fmaf(vv, sc, s);
        }
        if (seg == 0)      { tr0 += t; sd0 += s; ne0 += v0; }
        else if (seg == 1) { tr1 += t; sd1 += s; ne1 += v0; }
        else               { tr2 += t; sd2 += s; ne2 += v0; }
    }
    sdl[0][wv][lane] = sd0;
    sdl[1][wv][lane] = sd1;
    sdl[2][wv][lane] = sd2;
    float t0 = waveReduceSum(tr0), t1 = waveReduceSum(tr1), t2 = waveReduceSum(tr2);
    float n0 = waveReduceSum(ne0), n1 = waveReduceSum(ne1), n2 = waveReduceSum(ne2);
    if (lane == 0) {
        red[wv][0] = t0; red[wv][1] = t1; red[wv][2] = t2;
        red[wv][3] = n0; red[wv][4] = n1; red[wv][5] = n2;
    }
    __syncthreads();
    if (threadIdx.x < KC) {
        #pragma unroll
        for (int s2 = 0; s2 < 3; ++s2) {
            float a = sdl[s2][0][threadIdx.x] + sdl[s2][1][threadIdx.x]
                    + sdl[s2][2][threadIdx.x] + sdl[s2][3][threadIdx.x];
            atomicAdd(Sd + s2 * KC + threadIdx.x, a);
        }
    } else if (threadIdx.x < KC + 6) {
        int q = threadIdx.x - KC;
        float a = red[0][q] + red[1][q] + red[2][q] + red[3][q];
        atomicAdd(scal + q, a);
    }
}

// ---------------- K3 (fallback only): cs[k] = sum_n S[n,k] ----------------
__global__ __launch_bounds__(256) void k_cs(
    const float* __restrict__ S, float* __restrict__ cs, int N)
{
    const int lane = threadIdx.x & 63;
    const int wid = (blockIdx.x * blockDim.x + threadIdx.x) >> 6;
    const int nw = (gridDim.x * blockDim.x) >> 6;
    float a = 0.f;
    for (int row = wid; row < N; row += nw)
        a += S[(size_t)row * KC + lane];
    atomicAdd(cs + lane, a);
}

// ---------------- K4: P[k,d] = sum_n S[n,k] * F[n,d] ----------------
__global__ __launch_bounds__(256) void k_pool(
    const float* __restrict__ S, const float* __restrict__ F,
    float* __restrict__ P, int N)
{
    const int d = threadIdx.x;
    float acc[KC];
    #pragma unroll
    for (int k = 0; k < KC; ++k) acc[k] = 0.f;
    int rowsPer = (N + gridDim.x - 1) / gridDim.x;
    int n0 = blockIdx.x * rowsPer;
    int n1 = min(N, n0 + rowsPer);
    #pragma unroll 2
    for (int n = n0; n < n1; ++n) {
        float fv = F[(size_t)n * DF + d];
        const float* sp = S + (size_t)n * KC;
        #pragma unroll
        for (int k = 0; k < KC; ++k)
            acc[k] = fmaf(sp[k], fv, acc[k]);
    }
    #pragma unroll
    for (int k = 0; k < KC; ++k) atomicAdd(P + k * DF + d, acc[k]);
}

// ---------------- K5: epilogue ----------------
__global__ __launch_bounds__(256) void k_final(
    const float* __restrict__ P, const float* __restrict__ cs,
    const float* __restrict__ scal,
    const float* __restrict__ Sd,
    const float* __restrict__ lamdaPtr,
    float* __restrict__ out, int N, int lossIdx)
{
    const float SC = 1.0507009873554805f, AL = 1.6732632423543772f;
    for (int i = threadIdx.x + blockIdx.x * blockDim.x; i < KC * DF; i += gridDim.x * blockDim.x) {
        int k = i / DF;
        float x = P[i] / cs[k];
        float y = x > 0.f ? SC * x : SC * AL * (expf(x) - 1.f);
        out[i] = y;
    }
    if (blockIdx.x == 0 && threadIdx.x == 0) {
        float trF = scal[0], trR = scal[1], trB = scal[2];
        float neF = scal[3], neR = scal[4], neB = scal[5];
        float two_m = neF;
        float sdf = 0.f, sdr = 0.f, sdb = 0.f, csn = 0.f;
        for (int k = 0; k < KC; ++k) {
            sdf += Sd[0 * KC + k] * Sd[0 * KC + k];
            sdr += Sd[1 * KC + k] * Sd[1 * KC + k];
            sdb += Sd[2 * KC + k] * Sd[2 * KC + k];
            csn += cs[k] * cs[k];
        }
        float lossF = -(trF - sdf / 2.f / neF) / 2.f / two_m;
        float lossR = -(trR - sdr / 2.f / neR) / 2.f / two_m;
        float lossB = -(trB - sdb / 2.f / neB) / 2.f / two_m;
        float fairness = fabsf(lamdaPtr[0] * (lossR - lossB));
        float collapse = sqrtf(csn) / (float)N * sqrtf((float)KC) - 1.f;
        out[lossIdx] = fairness + lossF + 0.1f * collapse;
    }
}

extern "C" void kernel_launch(void* const* d_in, const int* in_sizes, int n_in,
                              void* d_out, int out_size, void* d_ws, size_t ws_size,
                              hipStream_t stream) {
    float* out = (float*)d_out;

    const int expected_sizes[13] = {12800000, 1600000, 1600000, 1600000,
                                    800000, 800000, 800000, 800000, 800000, 800000,
                                    16384, 64, 1};
    bool sizes_ok = (n_in == 13) && (out_size == 16384 + 12800000 / DF * KC + 1);
    if (sizes_ok) for (int i = 0; i < 13; ++i) if (in_sizes[i] != expected_sizes[i]) sizes_ok = false;
    if (!sizes_ok) {
        k_sentinel<<<64, 256, 0, stream>>>(out, 22222.0f, KC * DF);
        return;
    }

    const float* F  = (const float*)d_in[0];
    const int*   rF = (const int*)  d_in[1];
    const int*   cF = (const int*)  d_in[2];
    const float* vF = (const float*)d_in[3];
    const int*   rR = (const int*)  d_in[4];
    const int*   cR = (const int*)  d_in[5];
    const float* vR = (const float*)d_in[6];
    const int*   rB = (const int*)  d_in[7];
    const int*   cB = (const int*)  d_in[8];
    const float* vB = (const float*)d_in[9];
    const float* W  = (const float*)d_in[10];
    const float* B  = (const float*)d_in[11];
    const float* lam= (const float*)d_in[12];

    const int E   = in_sizes[1];
    const int E2r = in_sizes[4];
    const int E2b = in_sizes[7];
    const int N   = in_sizes[0] / DF;

    float* S = out + KC * DF;   // S [N,K] f32 in the output buffer

    // ws: [f32: scal 16 | cs 64 | Sd 192 | P 16384] [W2 hi/lo 65536 B] [S16 N*K*2 B]
    const size_t f32Bytes = (size_t)(16 + KC + 3 * KC + KC * DF) * sizeof(float); // 66624
    const size_t w2Bytes  = (size_t)2 * DF * KC * sizeof(ushort);                 // 65536
    const size_t s16Bytes = (size_t)N * KC * sizeof(__hip_bfloat16);
    const bool useMfma = ws_size >= f32Bytes + w2Bytes;
    const bool useBf16 = ws_size >= f32Bytes + w2Bytes + s16Bytes;
    if (ws_size < f32Bytes) {
        k_sentinel<<<64, 256, 0, stream>>>(out, 11111.0f, KC * DF);
        return;
    }
    float* scal = (float*)d_ws;
    float* cs   = scal + 16;
    float* Sd   = cs + KC;
    float* P    = Sd + 3 * KC;
    ushort* W2  = (ushort*)((char*)d_ws + f32Bytes);
    __hip_bfloat16* S16 = (__hip_bfloat16*)((char*)d_ws + f32Bytes + w2Bytes);
    const int zeroCount = 16 + KC + 3 * KC + KC * DF;

    k_zero<<<64, 256, 0, stream>>>(scal, zeroCount);
    if (useMfma) {
        const int NT = (N + 15) >> 4;
        k_prepW<<<64, 256, 0, stream>>>(W, W2);
        k_assign_mfma<<<(NT + 3) / 4, 256, 0, stream>>>(F, W2, B, S, S16, cs, N, useBf16 ? 1 : 0);
    } else {
        k_assign_valu<<<2048, 256, 0, stream>>>(F, W, B, S, N);
        k_cs<<<1024, 256, 0, stream>>>(S, cs, N);
    }
    if (useBf16) {
        k_edge3<__hip_bfloat16><<<2048, 256, 0, stream>>>(
            rF, cF, vF, E, rR, cR, vR, E2r, rB, cB, vB, E2b, S16, scal, Sd);
    } else {
        k_edge3<float><<<2048, 256, 0, stream>>>(
            rF, cF, vF, E, rR, cR, vR, E2r, rB, cB, vB, E2b, S, scal, Sd);
    }
    k_pool<<<256, 256, 0, stream>>>(S, F, P, N);
    k_final<<<64, 256, 0, stream>>>(P, cs, scal, Sd, lam, out, N, out_size - 1);
}